// Round 2
// baseline (267.841 us; speedup 1.0000x reference)
//
#include <hip/hip_runtime.h>

// Problem constants (match reference file)
constexpr int B = 32768;
constexpr int D = 1024;
constexpr int S = 64;
constexpr int O = 4;

// ---------------------------------------------------------------------------
// Strategy: rows are grouped by subject (counting sort: single-block LDS
// histogram + wave prefix scan -> atomic scatter into workspace perm[]), then
// the main kernel processes sorted rows with the current subject's ENTIRE W
// slice resident in 64 VGPRs (lane l owns d in [16l, 16l+16) = 16 float4 of
// W[s]).  Steady state per row: 4 coalesced float4 x-loads + 64 FMAs +
// 12-shuffle reduce, zero W loads.  W regs reload only at subject boundaries
// (~63 grid-wide) and once per wave.  This removes the 4:1 W:x gather traffic
// that made the 204 us kernel latency-bound at 0.66 TB/s effective.
//
// R1 hardening vs R0 (container died before profiling):
//  - NO hipMemsetAsync in kernel_launch: hist+scan fused into one
//    single-block kernel that zeroes its own LDS histogram.
//  - Double buffer is two NAMED register arrays (xbA/xbB) with an explicit
//    two-phase loop body: every register-array index is a compile-time
//    literal (rule #20 - runtime-indexed reg arrays go to scratch).
// ---------------------------------------------------------------------------

// Workspace layout (need 128 KiB + 256 B):
//   [0, 64) ints   : cursors (exclusive prefix, then atomic scatter cursors)
//   [64, 64+B)     : perm entries, packed (subject << 16) | row
constexpr int MAIN_BLOCKS   = 1024;                   // 4096 waves
constexpr int ROWS_PER_WAVE = B / (MAIN_BLOCKS * 4);  // 8

__global__ __launch_bounds__(1024) void hist_scan_kernel(
    const int* __restrict__ sid, int* __restrict__ cursors)
{
    __shared__ int h[S];
    const int t = threadIdx.x;
    if (t < S) h[t] = 0;
    __syncthreads();
    #pragma unroll 4
    for (int i = t; i < B; i += 1024)
        atomicAdd(&h[sid[i]], 1);
    __syncthreads();
    if (t < 64) {                         // first wave: 64-lane inclusive scan
        const int v = h[t];
        int xs = v;
        #pragma unroll
        for (int off = 1; off < 64; off <<= 1) {
            const int y = __shfl_up(xs, off, 64);
            if (t >= off) xs += y;
        }
        cursors[t] = xs - v;              // exclusive prefix
    }
}

__global__ __launch_bounds__(256) void scatter_kernel(
    const int* __restrict__ sid, int* __restrict__ cursors,
    unsigned* __restrict__ perm)
{
    for (int i = blockIdx.x * blockDim.x + threadIdx.x; i < B;
         i += gridDim.x * blockDim.x) {
        const int s = sid[i];
        const int pos = atomicAdd(&cursors[s], 1);
        perm[pos] = ((unsigned)s << 16) | (unsigned)i;   // row fits in 15 bits
    }
}

__global__ __launch_bounds__(256) void main_kernel(
    const float*    __restrict__ x,      // [B, D]
    const unsigned* __restrict__ perm,   // [B] packed (s<<16)|row, subject-sorted
    const float*    __restrict__ W,      // [S, D, O]
    const float*    __restrict__ bias,   // [S, O]
    float*          __restrict__ out)    // [B, O]
{
    const int lane = threadIdx.x & 63;
    const int wave = threadIdx.x >> 6;
    const int gw   = blockIdx.x * 4 + wave;       // 0..4095
    const int q    = lane >> 4;                   // output index this lane stores

    int p = gw * ROWS_PER_WAVE;
    const int pend = p + ROWS_PER_WAVE;

    const unsigned e = perm[p];                    // wave-uniform value
    int s   = (int)__builtin_amdgcn_readfirstlane(e >> 16);
    int row = (int)__builtin_amdgcn_readfirstlane(e & 0xFFFFu);

    // Register-resident W slice for subject s: lane l holds W[s][16l..16l+16)
    // as 16 float4 = 64 VGPR.  Reloaded only on subject change (rare: sorted).
    float4 wreg[16];
    {
        const float4* Wp = (const float4*)(W + (size_t)s * (D * O));
        #pragma unroll
        for (int k = 0; k < 16; ++k) wreg[k] = Wp[lane * 16 + k];
    }

    // Double-buffered x row in two NAMED buffers (all indices literal).
    float4 xbA[4], xbB[4];
    {
        const float4* xr = (const float4*)(x + ((size_t)row << 10));
        #pragma unroll
        for (int j = 0; j < 4; ++j) xbA[j] = xr[(lane << 2) + j];
    }

    // One phase: prefetch next row's x into XN, FMA current row from XC,
    // reduce + store, then (rarely) reload wreg at a subject boundary.
#define PHASE(XC, XN)                                                          \
    {                                                                          \
        int s_next = s, row_next = row;                                        \
        const bool more = (p + 1 < pend);                                      \
        if (more) {                                                            \
            const unsigned en = perm[p + 1];                                   \
            s_next   = (int)__builtin_amdgcn_readfirstlane(en >> 16);          \
            row_next = (int)__builtin_amdgcn_readfirstlane(en & 0xFFFFu);      \
            const float4* xrn = (const float4*)(x + ((size_t)row_next << 10)); \
            _Pragma("unroll")                                                  \
            for (int j = 0; j < 4; ++j) XN[j] = xrn[(lane << 2) + j];          \
        }                                                                      \
        float a0 = 0.f, a1 = 0.f, a2 = 0.f, a3 = 0.f;                          \
        _Pragma("unroll")                                                      \
        for (int j = 0; j < 4; ++j) {                                          \
            const float4 xv = XC[j];                                           \
            const float4 w0 = wreg[4 * j + 0];                                 \
            const float4 w1 = wreg[4 * j + 1];                                 \
            const float4 w2 = wreg[4 * j + 2];                                 \
            const float4 w3 = wreg[4 * j + 3];                                 \
            a0 += xv.x * w0.x; a1 += xv.x * w0.y;                              \
            a2 += xv.x * w0.z; a3 += xv.x * w0.w;                              \
            a0 += xv.y * w1.x; a1 += xv.y * w1.y;                              \
            a2 += xv.y * w1.z; a3 += xv.y * w1.w;                              \
            a0 += xv.z * w2.x; a1 += xv.z * w2.y;                              \
            a2 += xv.z * w2.z; a3 += xv.z * w2.w;                              \
            a0 += xv.w * w3.x; a1 += xv.w * w3.y;                              \
            a2 += xv.w * w3.z; a3 += xv.w * w3.w;                              \
        }                                                                      \
        const float bb = bias[(s << 2) + q];                                   \
        _Pragma("unroll")                                                      \
        for (int m = 16; m <= 32; m <<= 1) {                                   \
            a0 += __shfl_xor(a0, m, 64);                                       \
            a1 += __shfl_xor(a1, m, 64);                                       \
            a2 += __shfl_xor(a2, m, 64);                                       \
            a3 += __shfl_xor(a3, m, 64);                                       \
        }                                                                      \
        float v = (q == 0) ? a0 : (q == 1) ? a1 : (q == 2) ? a2 : a3;          \
        _Pragma("unroll")                                                      \
        for (int m = 1; m <= 8; m <<= 1)                                       \
            v += __shfl_xor(v, m, 64);                                         \
        if ((lane & 15) == 0)                                                  \
            out[((size_t)row << 2) + q] = v + bb;                              \
        if (more && s_next != s) {                                             \
            const float4* Wp = (const float4*)(W + (size_t)s_next * (D * O));  \
            _Pragma("unroll")                                                  \
            for (int k = 0; k < 16; ++k) wreg[k] = Wp[lane * 16 + k];          \
        }                                                                      \
        s = s_next; row = row_next; ++p;                                       \
    }

    #pragma unroll 1
    for (int it2 = 0; it2 < ROWS_PER_WAVE / 2; ++it2) {
        PHASE(xbA, xbB)
        PHASE(xbB, xbA)
    }
#undef PHASE
}

extern "C" void kernel_launch(void* const* d_in, const int* in_sizes, int n_in,
                              void* d_out, int out_size, void* d_ws, size_t ws_size,
                              hipStream_t stream) {
    const float* x    = (const float*)d_in[0];   // [B, D]
    const int*   sid  = (const int*)d_in[1];     // [B]
    const float* W    = (const float*)d_in[2];   // [S, D, O]
    const float* bias = (const float*)d_in[3];   // [S, O]
    float* out = (float*)d_out;                  // [B, O]

    int*      cursors = (int*)d_ws;
    unsigned* perm    = (unsigned*)(cursors + 64);

    hist_scan_kernel<<<1, 1024, 0, stream>>>(sid, cursors);
    scatter_kernel<<<128, 256, 0, stream>>>(sid, cursors, perm);
    main_kernel<<<MAIN_BLOCKS, 256, 0, stream>>>(x, perm, W, bias, out);
}

// Round 3
// 204.015 us; speedup vs baseline: 1.3128x; 1.3128x over previous
//
#include <hip/hip_runtime.h>

// Problem constants (match reference file)
constexpr int B = 32768;
constexpr int D = 1024;
constexpr int S = 64;
constexpr int O = 4;

// ---------------------------------------------------------------------------
// Design: counting-sort rows by subject, then main kernel walks sorted rows
// with the subject's ENTIRE W slice register-resident (64 VGPR).
//
// R2 post-mortem -> R3 changes:
//  * Scatter had 32768 device-scope atomics onto 64 cursors in ~2 cache
//    lines (cross-XCD serialization ~ tens of us).  Now ZERO global atomics:
//    per-block count matrix [64][64] (kernel A), each scatter block derives
//    its own offsets from the matrix and ranks via LDS atomics (kernel C).
//  * Main kernel x loads were 64B-strided across lanes (4x cache-line
//    transactions).  Remapped: instr j, lane l reads float4 64j+l -> 1KB
//    contiguous per instruction.  wreg[4j+c] = W row 256j+4l+c matches.
//  * Per-row perm load dependency removed: 8 perm entries loaded up-front
//    as two broadcast uint4; 8 phases fully unrolled, literal indices only.
// ---------------------------------------------------------------------------

// Workspace layout:
//   [0, 16 KiB)          : cnt[64][64]  per-block subject counts
//   [16 KiB, 16K + 128K) : perm entries, packed (subject << 16) | row
constexpr int SORT_BLOCKS  = 64;
constexpr int CHUNK        = B / SORT_BLOCKS;          // 512 rows per block
constexpr int MAIN_BLOCKS  = 1024;                     // 4096 waves
constexpr int ROWS_PER_WAVE = B / (MAIN_BLOCKS * 4);   // 8

__global__ __launch_bounds__(512) void count_kernel(
    const int* __restrict__ sid, int* __restrict__ cnt)   // cnt[64][64]
{
    __shared__ int h[S];
    const int t = threadIdx.x;
    if (t < S) h[t] = 0;
    __syncthreads();
    const int i = blockIdx.x * CHUNK + t;                 // one row per thread
    atomicAdd(&h[sid[i]], 1);
    __syncthreads();
    if (t < S) cnt[blockIdx.x * S + t] = h[t];
}

__global__ __launch_bounds__(512) void scatter_kernel(
    const int* __restrict__ sid, const int* __restrict__ cnt,
    unsigned* __restrict__ perm)
{
    __shared__ int base_lds[S];
    __shared__ int cur_lds[S];
    const int t = threadIdx.x;
    const int b = blockIdx.x;

    if (t < S) {                        // wave 0: derive this block's offsets
        int before = 0, total = 0;
        #pragma unroll 8
        for (int bb = 0; bb < SORT_BLOCKS; ++bb) {
            const int c = cnt[bb * S + t];     // coalesced row read
            if (bb < b) before += c;
            total += c;
        }
        int xs = total;                 // inclusive scan over subjects
        #pragma unroll
        for (int off = 1; off < 64; off <<= 1) {
            const int y = __shfl_up(xs, off, 64);
            if (t >= off) xs += y;
        }
        base_lds[t] = (xs - total) + before;   // global exclusive prefix
        cur_lds[t]  = 0;
    }
    __syncthreads();

    const int i = b * CHUNK + t;                // one row per thread
    const int s = sid[i];
    const int r = atomicAdd(&cur_lds[s], 1);    // LDS-only ranking
    perm[base_lds[s] + r] = ((unsigned)s << 16) | (unsigned)i;
}

__global__ __launch_bounds__(256, 4) void main_kernel(
    const float*    __restrict__ x,      // [B, D]
    const unsigned* __restrict__ perm,   // [B] packed (s<<16)|row, sorted
    const float*    __restrict__ W,      // [S, D, O]
    const float*    __restrict__ bias,   // [S, O]
    float*          __restrict__ out)    // [B, O]
{
    const int lane = threadIdx.x & 63;
    const int wave = threadIdx.x >> 6;
    const int gw   = blockIdx.x * 4 + wave;       // 0..4095
    const int q    = lane >> 4;                   // output index this lane stores

    const int p = gw * ROWS_PER_WAVE;             // 8 entries, 32B-aligned

    // All 8 perm entries up-front (wave-uniform broadcast loads).
    const uint4 pa = ((const uint4*)(perm + p))[0];
    const uint4 pb = ((const uint4*)(perm + p))[1];
    const unsigned e0 = pa.x, e1 = pa.y, e2 = pa.z, e3 = pa.w;
    const unsigned e4 = pb.x, e5 = pb.y, e6 = pb.z, e7 = pb.w;

    int s   = (int)__builtin_amdgcn_readfirstlane(e0 >> 16);
    int row = (int)__builtin_amdgcn_readfirstlane(e0 & 0xFFFFu);

    // W slice for subject s: wreg[4j+c] = W row (256j + 4*lane + c), 64 VGPR.
    float4 wreg[16];
#define RELOAD_W(SP)                                                           \
    {                                                                          \
        const float4* Wp = (const float4*)(W + (size_t)(SP) * (D * O));        \
        _Pragma("unroll")                                                      \
        for (int jj = 0; jj < 4; ++jj) {                                       \
            _Pragma("unroll")                                                  \
            for (int cc = 0; cc < 4; ++cc)                                     \
                wreg[4 * jj + cc] = Wp[256 * jj + 4 * lane + cc];              \
        }                                                                      \
    }
    RELOAD_W(s)

    // x double buffer: instr j, lane l -> float4 64j+l (1KB contiguous/instr).
    float4 xbA[4], xbB[4];
    {
        const float4* xr = (const float4*)(x + ((size_t)row << 10));
        #pragma unroll
        for (int j = 0; j < 4; ++j) xbA[j] = xr[64 * j + lane];
    }

#define FMA_REDUCE_STORE(XC)                                                   \
    {                                                                          \
        float a0 = 0.f, a1 = 0.f, a2 = 0.f, a3 = 0.f;                          \
        _Pragma("unroll")                                                      \
        for (int j = 0; j < 4; ++j) {                                          \
            const float4 xv = XC[j];                                           \
            const float4 w0 = wreg[4 * j + 0];                                 \
            const float4 w1 = wreg[4 * j + 1];                                 \
            const float4 w2 = wreg[4 * j + 2];                                 \
            const float4 w3 = wreg[4 * j + 3];                                 \
            a0 += xv.x * w0.x; a1 += xv.x * w0.y;                              \
            a2 += xv.x * w0.z; a3 += xv.x * w0.w;                              \
            a0 += xv.y * w1.x; a1 += xv.y * w1.y;                              \
            a2 += xv.y * w1.z; a3 += xv.y * w1.w;                              \
            a0 += xv.z * w2.x; a1 += xv.z * w2.y;                              \
            a2 += xv.z * w2.z; a3 += xv.z * w2.w;                              \
            a0 += xv.w * w3.x; a1 += xv.w * w3.y;                              \
            a2 += xv.w * w3.z; a3 += xv.w * w3.w;                              \
        }                                                                      \
        const float bb = bias[(s << 2) + q];                                   \
        _Pragma("unroll")                                                      \
        for (int m = 16; m <= 32; m <<= 1) {                                   \
            a0 += __shfl_xor(a0, m, 64);                                       \
            a1 += __shfl_xor(a1, m, 64);                                       \
            a2 += __shfl_xor(a2, m, 64);                                       \
            a3 += __shfl_xor(a3, m, 64);                                       \
        }                                                                      \
        float v = (q == 0) ? a0 : (q == 1) ? a1 : (q == 2) ? a2 : a3;          \
        _Pragma("unroll")                                                      \
        for (int m = 1; m <= 8; m <<= 1)                                       \
            v += __shfl_xor(v, m, 64);                                         \
        if ((lane & 15) == 0)                                                  \
            out[((size_t)row << 2) + q] = v + bb;                              \
    }

    // Phase: prefetch next row's x into XN, compute current row from XC,
    // then (rarely, wave-uniform) reload wreg at a subject boundary.
#define PHASE(ENXT, XC, XN)                                                    \
    {                                                                          \
        const int s_n   = (int)__builtin_amdgcn_readfirstlane((ENXT) >> 16);   \
        const int row_n = (int)__builtin_amdgcn_readfirstlane((ENXT) & 0xFFFFu);\
        const float4* xrn = (const float4*)(x + ((size_t)row_n << 10));        \
        _Pragma("unroll")                                                      \
        for (int j = 0; j < 4; ++j) XN[j] = xrn[64 * j + lane];                \
        FMA_REDUCE_STORE(XC)                                                   \
        if (s_n != s) RELOAD_W(s_n)                                            \
        s = s_n; row = row_n;                                                  \
    }

    PHASE(e1, xbA, xbB)
    PHASE(e2, xbB, xbA)
    PHASE(e3, xbA, xbB)
    PHASE(e4, xbB, xbA)
    PHASE(e5, xbA, xbB)
    PHASE(e6, xbB, xbA)
    PHASE(e7, xbA, xbB)
    FMA_REDUCE_STORE(xbB)   // last row, no prefetch

#undef PHASE
#undef FMA_REDUCE_STORE
#undef RELOAD_W
}

extern "C" void kernel_launch(void* const* d_in, const int* in_sizes, int n_in,
                              void* d_out, int out_size, void* d_ws, size_t ws_size,
                              hipStream_t stream) {
    const float* x    = (const float*)d_in[0];   // [B, D]
    const int*   sid  = (const int*)d_in[1];     // [B]
    const float* W    = (const float*)d_in[2];   // [S, D, O]
    const float* bias = (const float*)d_in[3];   // [S, O]
    float* out = (float*)d_out;                  // [B, O]

    int*      cnt  = (int*)d_ws;                       // [64][64]
    unsigned* perm = (unsigned*)(cnt + SORT_BLOCKS * S); // 16 KiB offset

    count_kernel<<<SORT_BLOCKS, CHUNK, 0, stream>>>(sid, cnt);
    scatter_kernel<<<SORT_BLOCKS, CHUNK, 0, stream>>>(sid, cnt, perm);
    main_kernel<<<MAIN_BLOCKS, 256, 0, stream>>>(x, perm, W, bias, out);
}